// Round 3
// baseline (725.503 us; speedup 1.0000x reference)
//
#include <hip/hip_runtime.h>

// ---------------------------------------------------------------------------
// BitfieldLinear via rank-structure split:
//   W[o,:] = r_o * basis[idx_o,:] + s_o * (q[o,:]-128)/127
//   y      = r_o * P[m, idx_o] + (a_m * s_o/127) * (xq @ qb^T) + bias
// where P = x @ basis^T  (bf16 MFMA, [M,256]),
//       xq = per-row int8 quant of x (scale a_m), qb = int8 (q-128)  (i8 MFMA).
// R2 bug fixed: p_gemm basis staging was missing the n0 block offset.
// ---------------------------------------------------------------------------

typedef __bf16 bf16x8 __attribute__((ext_vector_type(8)));
typedef float f32x4 __attribute__((ext_vector_type(4)));
typedef int i32x4 __attribute__((ext_vector_type(4)));
typedef unsigned short u16x8 __attribute__((ext_vector_type(8)));

__device__ __forceinline__ void load_lds16(const void* g, void* l) {
    __builtin_amdgcn_global_load_lds(
        (__attribute__((address_space(1))) void*)(void*)g,
        (__attribute__((address_space(3))) void*)l,
        16, 0, 0);
}

// ---------------- Kernel 1: per-row int8 quantization of x -----------------
__global__ void quant_x_kernel(const float* __restrict__ x,
                               signed char* __restrict__ xq,
                               float* __restrict__ arow, int K) {
    const int m = blockIdx.x;
    const float* row = x + (size_t)m * K;
    const int base = threadIdx.x * 16;
    float4 v[4];
#pragma unroll
    for (int j = 0; j < 4; ++j) v[j] = *(const float4*)(row + base + j * 4);

    float lmax = 0.f;
#pragma unroll
    for (int j = 0; j < 4; ++j) {
        lmax = fmaxf(lmax, fabsf(v[j].x));
        lmax = fmaxf(lmax, fabsf(v[j].y));
        lmax = fmaxf(lmax, fabsf(v[j].z));
        lmax = fmaxf(lmax, fabsf(v[j].w));
    }
#pragma unroll
    for (int off = 32; off; off >>= 1)
        lmax = fmaxf(lmax, __shfl_xor(lmax, off));
    __shared__ float smax[4];
    if ((threadIdx.x & 63) == 0) smax[threadIdx.x >> 6] = lmax;
    __syncthreads();
    const float mx = fmaxf(fmaxf(smax[0], smax[1]), fmaxf(smax[2], smax[3]));
    const float inv = mx > 0.f ? 127.0f / mx : 0.0f;
    if (threadIdx.x == 0) arow[m] = mx * (1.0f / 127.0f);

    union { signed char c[16]; i32x4 w; } pk;
#pragma unroll
    for (int j = 0; j < 4; ++j) {
        pk.c[j * 4 + 0] = (signed char)(int)rintf(v[j].x * inv);
        pk.c[j * 4 + 1] = (signed char)(int)rintf(v[j].y * inv);
        pk.c[j * 4 + 2] = (signed char)(int)rintf(v[j].z * inv);
        pk.c[j * 4 + 3] = (signed char)(int)rintf(v[j].w * inv);
    }
    *(i32x4*)(xq + (size_t)m * K + base) = pk.w;
}

// ---------------- Kernel 2: pack residual int32 -> int8 (q-128) ------------
__global__ void pack_q_kernel(const int4* __restrict__ q4,
                              unsigned int* __restrict__ out, int n4) {
    const int i = blockIdx.x * blockDim.x + threadIdx.x;
    if (i >= n4) return;
    int4 a = q4[i];
    unsigned int w = ((unsigned)(a.x - 128) & 0xFFu)
                   | (((unsigned)(a.y - 128) & 0xFFu) << 8)
                   | (((unsigned)(a.z - 128) & 0xFFu) << 16)
                   | (((unsigned)(a.w - 128) & 0xFFu) << 24);
    out[i] = w;
}

// ---------------- Kernel 3: P = x @ basis^T (bf16 MFMA) --------------------
// BM=64, BN=128, BK=32. 4 waves, each wave = 64 rows x 32 cols (4x2 MFMA).
__global__ void p_gemm_kernel(const float* __restrict__ x,     // [M,K] fp32
                              const float* __restrict__ basis, // [256,K] fp32
                              float* __restrict__ P,           // [M,256]
                              int M, int K) {
    const int NB = 256;
    __shared__ __align__(16) unsigned short As[64 * 32];
    __shared__ __align__(16) unsigned short Bs[128 * 32];

    const int tid  = threadIdx.x;
    const int lane = tid & 63;
    const int wv   = tid >> 6;        // wave covers cols wv*32..wv*32+31
    const int m0 = blockIdx.y * 64;
    const int n0 = blockIdx.x * 128;
    const int lr = lane & 15;
    const int kg = lane >> 4;

    f32x4 acc[4][2];
#pragma unroll
    for (int mi = 0; mi < 4; ++mi)
#pragma unroll
        for (int ni = 0; ni < 2; ++ni)
            acc[mi][ni] = (f32x4){0.f, 0.f, 0.f, 0.f};

    const int arow_ = tid >> 2, acol = (tid & 3) * 8;
    const int lb0 = tid, lb1 = tid + 256;
    const int br0 = lb0 >> 2, bc0 = (lb0 & 3) * 8;
    const int br1 = lb1 >> 2, bc1 = (lb1 & 3) * 8;

    const float* Agp = x + (size_t)(m0 + arow_) * K + acol;
    const float* Bg0 = basis + (size_t)(n0 + br0) * K + bc0;   // FIXED: + n0
    const float* Bg1 = basis + (size_t)(n0 + br1) * K + bc1;   // FIXED: + n0

    for (int k0 = 0; k0 < K; k0 += 32) {
        float4 a0 = *(const float4*)(Agp + k0);
        float4 a1 = *(const float4*)(Agp + k0 + 4);
        float4 b00 = *(const float4*)(Bg0 + k0);
        float4 b01 = *(const float4*)(Bg0 + k0 + 4);
        float4 b10 = *(const float4*)(Bg1 + k0);
        float4 b11 = *(const float4*)(Bg1 + k0 + 4);
        union { bf16x8 b; u16x8 u; } ca, cb0, cb1;
        ca.b[0] = (__bf16)a0.x; ca.b[1] = (__bf16)a0.y;
        ca.b[2] = (__bf16)a0.z; ca.b[3] = (__bf16)a0.w;
        ca.b[4] = (__bf16)a1.x; ca.b[5] = (__bf16)a1.y;
        ca.b[6] = (__bf16)a1.z; ca.b[7] = (__bf16)a1.w;
        cb0.b[0] = (__bf16)b00.x; cb0.b[1] = (__bf16)b00.y;
        cb0.b[2] = (__bf16)b00.z; cb0.b[3] = (__bf16)b00.w;
        cb0.b[4] = (__bf16)b01.x; cb0.b[5] = (__bf16)b01.y;
        cb0.b[6] = (__bf16)b01.z; cb0.b[7] = (__bf16)b01.w;
        cb1.b[0] = (__bf16)b10.x; cb1.b[1] = (__bf16)b10.y;
        cb1.b[2] = (__bf16)b10.z; cb1.b[3] = (__bf16)b10.w;
        cb1.b[4] = (__bf16)b11.x; cb1.b[5] = (__bf16)b11.y;
        cb1.b[6] = (__bf16)b11.z; cb1.b[7] = (__bf16)b11.w;
        *(u16x8*)(As + tid * 8) = ca.u;
        *(u16x8*)(Bs + lb0 * 8) = cb0.u;
        *(u16x8*)(Bs + lb1 * 8) = cb1.u;
        __syncthreads();

        bf16x8 af[4], bfr[2];
#pragma unroll
        for (int mi = 0; mi < 4; ++mi)
            af[mi] = __builtin_bit_cast(bf16x8,
                *(const u16x8*)(As + (mi * 16 + lr) * 32 + kg * 8));
#pragma unroll
        for (int ni = 0; ni < 2; ++ni)
            bfr[ni] = __builtin_bit_cast(bf16x8,
                *(const u16x8*)(Bs + (wv * 32 + ni * 16 + lr) * 32 + kg * 8));
#pragma unroll
        for (int mi = 0; mi < 4; ++mi)
#pragma unroll
            for (int ni = 0; ni < 2; ++ni)
                acc[mi][ni] = __builtin_amdgcn_mfma_f32_16x16x32_bf16(
                    af[mi], bfr[ni], acc[mi][ni], 0, 0, 0);
        __syncthreads();
    }

#pragma unroll
    for (int ni = 0; ni < 2; ++ni) {
        const int n = n0 + wv * 32 + ni * 16 + lr;
#pragma unroll
        for (int mi = 0; mi < 4; ++mi) {
            const int mbase = m0 + mi * 16 + kg * 4;
#pragma unroll
            for (int rg = 0; rg < 4; ++rg)
                P[(size_t)(mbase + rg) * NB + n] = acc[mi][ni][rg];
        }
    }
}

// ---------------- Kernel 4: y2 = xq @ qb^T (i8 MFMA) + fused epilogue ------
// 128x128 tile, BK=64 int8 (64 bytes/row). 4 waves 2x2, each 64x64 (4x4 MFMA).
__global__ void gemm_i8_kernel(const signed char* __restrict__ Xq, // [M,K]
                               const signed char* __restrict__ Qb, // [N,K]
                               const float* __restrict__ arow,     // [M]
                               const int* __restrict__ codes,      // [N]
                               const float* __restrict__ scales,   // [N]
                               const float* __restrict__ bias,     // [N]
                               const float* __restrict__ P,        // [M,256]
                               float* __restrict__ out,            // [M,N]
                               int M, int N, int K) {
    __shared__ __align__(16) signed char As[128 * 64];
    __shared__ __align__(16) signed char Bs[128 * 64];

    const int tid  = threadIdx.x;
    const int lane = tid & 63;
    const int wv   = tid >> 6;
    const int wrow = wv >> 1;
    const int wcol = wv & 1;
    const int m0 = blockIdx.y * 128;
    const int n0 = blockIdx.x * 128;
    const int lr = lane & 15;
    const int kg = lane >> 4;

    i32x4 acc[4][4];
#pragma unroll
    for (int mi = 0; mi < 4; ++mi)
#pragma unroll
        for (int ni = 0; ni < 4; ++ni)
            acc[mi][ni] = (i32x4){0, 0, 0, 0};

    const int lin0 = tid, lin1 = tid + 256;
    const int ar0 = lin0 >> 2, ac0 = (lin0 & 3) * 16;
    const int ar1 = lin1 >> 2, ac1 = (lin1 & 3) * 16;

    const signed char* Ag0 = Xq + (size_t)(m0 + ar0) * K + ac0;
    const signed char* Ag1 = Xq + (size_t)(m0 + ar1) * K + ac1;
    const signed char* Bg0 = Qb + (size_t)(n0 + ar0) * K + ac0;
    const signed char* Bg1 = Qb + (size_t)(n0 + ar1) * K + ac1;

    signed char* Al0 = As + lin0 * 16;
    signed char* Al1 = As + lin1 * 16;
    signed char* Bl0 = Bs + lin0 * 16;
    signed char* Bl1 = Bs + lin1 * 16;

    for (int k0 = 0; k0 < K; k0 += 64) {
        load_lds16(Ag0 + k0, Al0);
        load_lds16(Ag1 + k0, Al1);
        load_lds16(Bg0 + k0, Bl0);
        load_lds16(Bg1 + k0, Bl1);
        __syncthreads();

        i32x4 af[4], bfr[4];
#pragma unroll
        for (int mi = 0; mi < 4; ++mi)
            af[mi] = *(const i32x4*)(As + (wrow * 64 + mi * 16 + lr) * 64 + kg * 16);
#pragma unroll
        for (int ni = 0; ni < 4; ++ni)
            bfr[ni] = *(const i32x4*)(Bs + (wcol * 64 + ni * 16 + lr) * 64 + kg * 16);
#pragma unroll
        for (int mi = 0; mi < 4; ++mi)
#pragma unroll
            for (int ni = 0; ni < 4; ++ni)
                acc[mi][ni] = __builtin_amdgcn_mfma_i32_16x16x64_i8(
                    af[mi], bfr[ni], acc[mi][ni], 0, 0, 0);
        __syncthreads();
    }

    float av[4][4];
#pragma unroll
    for (int mi = 0; mi < 4; ++mi)
#pragma unroll
        for (int rg = 0; rg < 4; ++rg)
            av[mi][rg] = arow[m0 + wrow * 64 + mi * 16 + kg * 4 + rg];

#pragma unroll
    for (int ni = 0; ni < 4; ++ni) {
        const int n = n0 + wcol * 64 + ni * 16 + lr;
        const int code = codes[n];
        const int c = code & 0xFF;
        const float r = (float)((code >> 8) & 0xFFFF) * (1.0f / 65535.0f);
        const float so = scales[n] * (1.0f / 127.0f);
        const float bv = bias[n];
#pragma unroll
        for (int mi = 0; mi < 4; ++mi) {
            const int mbase = m0 + wrow * 64 + mi * 16 + kg * 4;
#pragma unroll
            for (int rg = 0; rg < 4; ++rg) {
                const int m = mbase + rg;
                const float y = av[mi][rg] * so * (float)acc[mi][ni][rg]
                              + r * P[(size_t)m * 256 + c] + bv;
                out[(size_t)m * N + n] = y;
            }
        }
    }
}

// ---------------------------------------------------------------------------
extern "C" void kernel_launch(void* const* d_in, const int* in_sizes, int n_in,
                              void* d_out, int out_size, void* d_ws, size_t ws_size,
                              hipStream_t stream) {
    const float* x        = (const float*)d_in[0];
    const int*   codes    = (const int*)d_in[1];
    const float* basis    = (const float*)d_in[2];
    const int*   q        = (const int*)d_in[3];
    const float* scales   = (const float*)d_in[4];
    const float* bias     = (const float*)d_in[5];
    float* out = (float*)d_out;

    const int BASIS = 256;
    const int K = in_sizes[2] / BASIS;   // 4096
    const int N = in_sizes[1];           // 4096
    const int M = in_sizes[0] / K;       // 8192

    char* ws = (char*)d_ws;
    signed char* Xq = (signed char*)ws;                 // M*K int8
    size_t off = (size_t)M * K;
    float* Arow = (float*)(ws + off);                   // M fp32
    off += (size_t)M * sizeof(float);
    signed char* Qb = (signed char*)(ws + off);         // N*K int8
    off += (size_t)N * K;
    float* P = (float*)(ws + off);                      // M*256 fp32

    quant_x_kernel<<<M, 256, 0, stream>>>(x, Xq, Arow, K);
    pack_q_kernel<<<(N * K / 4 + 255) / 256, 256, 0, stream>>>(
        (const int4*)q, (unsigned int*)Qb, N * K / 4);
    p_gemm_kernel<<<dim3(BASIS / 128, M / 64), 256, 0, stream>>>(x, basis, P, M, K);
    gemm_i8_kernel<<<dim3(N / 128, M / 128), 256, 0, stream>>>(
        Xq, Qb, Arow, codes, scales, bias, P, out, M, N, K);
}

// Round 4
// 535.205 us; speedup vs baseline: 1.3556x; 1.3556x over previous
//
#include <hip/hip_runtime.h>

// ---------------------------------------------------------------------------
// BitfieldLinear via rank-structure split:
//   y = r_n * P[m, c_n] + (a_m * s_n/127) * (xq @ qb^T) + bias
//   P = x @ basis^T  (bf16 MFMA, stored bf16 [M,256])
// R4: fast p_gemm (global_load_lds, 512 blocks), XOR-swizzled LDS (2-way),
//     P gathered pre-K-loop into LDS stash, NT output stores.
// ---------------------------------------------------------------------------

typedef __bf16 bf16x8 __attribute__((ext_vector_type(8)));
typedef float f32x4 __attribute__((ext_vector_type(4)));
typedef int i32x4 __attribute__((ext_vector_type(4)));
typedef unsigned short u16x8 __attribute__((ext_vector_type(8)));

__device__ __forceinline__ unsigned short f2bf(float f) {
    union { float f; unsigned int u; } c; c.f = f;
    unsigned int u = c.u;
    u += 0x7fffu + ((u >> 16) & 1u);
    return (unsigned short)(u >> 16);
}
__device__ __forceinline__ float bf2f(unsigned short h) {
    union { unsigned int u; float f; } c; c.u = ((unsigned int)h) << 16;
    return c.f;
}

__device__ __forceinline__ void load_lds16(const void* g, void* l) {
    __builtin_amdgcn_global_load_lds(
        (__attribute__((address_space(1))) void*)(void*)g,
        (__attribute__((address_space(3))) void*)l,
        16, 0, 0);
}

// swizzle: physical 16B-slot p -> (row, chunk) byte offset in a tile whose
// rows are 64 B (4 chunks). v = (p&7) ^ ((p>>3)&7); row = (p>>3)*2 + (v>>2).
__device__ __forceinline__ int swz_decode(int p, int row_bytes) {
    const int g = p >> 3, t = p & 7, v = t ^ (g & 7);
    const int row = g * 2 + (v >> 2), chunk = v & 3;
    return row * row_bytes + chunk * 16;
}

// ---------------- x fp32 -> bf16 (also used for basis) ---------------------
__global__ void cvt_bf16_kernel(const float4* __restrict__ in4,
                                ushort4* __restrict__ out4, int n4) {
    int i = blockIdx.x * blockDim.x + threadIdx.x;
    const int stride = gridDim.x * blockDim.x;
    for (; i < n4; i += stride) {
        float4 v = in4[i];
        ushort4 o;
        o.x = f2bf(v.x); o.y = f2bf(v.y); o.z = f2bf(v.z); o.w = f2bf(v.w);
        out4[i] = o;
    }
}

// ---------------- per-row int8 quantization of x ---------------------------
__global__ void quant_x_kernel(const float* __restrict__ x,
                               signed char* __restrict__ xq,
                               float* __restrict__ arow, int K) {
    const int m = blockIdx.x;
    const float* row = x + (size_t)m * K;
    const int base = threadIdx.x * 16;
    float4 v[4];
#pragma unroll
    for (int j = 0; j < 4; ++j) v[j] = *(const float4*)(row + base + j * 4);

    float lmax = 0.f;
#pragma unroll
    for (int j = 0; j < 4; ++j) {
        lmax = fmaxf(lmax, fabsf(v[j].x));
        lmax = fmaxf(lmax, fabsf(v[j].y));
        lmax = fmaxf(lmax, fabsf(v[j].z));
        lmax = fmaxf(lmax, fabsf(v[j].w));
    }
#pragma unroll
    for (int off = 32; off; off >>= 1)
        lmax = fmaxf(lmax, __shfl_xor(lmax, off));
    __shared__ float smax[4];
    if ((threadIdx.x & 63) == 0) smax[threadIdx.x >> 6] = lmax;
    __syncthreads();
    const float mx = fmaxf(fmaxf(smax[0], smax[1]), fmaxf(smax[2], smax[3]));
    const float inv = mx > 0.f ? 127.0f / mx : 0.0f;
    if (threadIdx.x == 0) arow[m] = mx * (1.0f / 127.0f);

    union { signed char c[16]; i32x4 w; } pk;
#pragma unroll
    for (int j = 0; j < 4; ++j) {
        pk.c[j * 4 + 0] = (signed char)(int)rintf(v[j].x * inv);
        pk.c[j * 4 + 1] = (signed char)(int)rintf(v[j].y * inv);
        pk.c[j * 4 + 2] = (signed char)(int)rintf(v[j].z * inv);
        pk.c[j * 4 + 3] = (signed char)(int)rintf(v[j].w * inv);
    }
    *(i32x4*)(xq + (size_t)m * K + base) = pk.w;
}

// ---------------- pack residual int32 -> int8 (q-128) ----------------------
__global__ void pack_q_kernel(const int4* __restrict__ q4,
                              unsigned int* __restrict__ out, int n4) {
    const int i = blockIdx.x * blockDim.x + threadIdx.x;
    if (i >= n4) return;
    int4 a = q4[i];
    unsigned int w = ((unsigned)(a.x - 128) & 0xFFu)
                   | (((unsigned)(a.y - 128) & 0xFFu) << 8)
                   | (((unsigned)(a.z - 128) & 0xFFu) << 16)
                   | (((unsigned)(a.w - 128) & 0xFFu) << 24);
    out[i] = w;
}

// ---------------- P = Xb @ Bb^T, bf16 out ----------------------------------
// TILE 64x64, BK=32. 4 waves; wave wv computes rows wv*16..+15 x all 64 cols.
__global__ void p_gemm_kernel(const unsigned short* __restrict__ Xb, // [M,K]
                              const unsigned short* __restrict__ Bb, // [256,K]
                              unsigned short* __restrict__ Pbf,      // [M,256]
                              int M, int K) {
    __shared__ __align__(16) unsigned short As[64 * 32];
    __shared__ __align__(16) unsigned short Bs[64 * 32];

    const int tid  = threadIdx.x;
    const int lane = tid & 63;
    const int wv   = tid >> 6;
    const int m0 = blockIdx.y * 64;
    const int n0 = blockIdx.x * 64;
    const int lr = lane & 15;
    const int kg = lane >> 4;
    const int swz = (lr >> 1) & 7;

    f32x4 acc[4];
#pragma unroll
    for (int ni = 0; ni < 4; ++ni) acc[ni] = (f32x4){0.f, 0.f, 0.f, 0.f};

    // staging: 256 slots each side; slot = tid. row_bytes = 64 (32 bf16).
    const int goff = swz_decode(tid, 64);  // bytes within tile
    const unsigned short* Agp = Xb + (size_t)m0 * K + (goff >> 6) * K + ((goff & 63) >> 1);
    const unsigned short* Bgp = Bb + (size_t)n0 * K + (goff >> 6) * K + ((goff & 63) >> 1);
    unsigned short* Al = As + tid * 8;
    unsigned short* Bl = Bs + tid * 8;

    const int cidx = (((lr & 1) << 2) | kg) ^ swz;  // swizzled chunk id 0..7

    for (int k0 = 0; k0 < K; k0 += 32) {
        load_lds16(Agp + k0, Al);
        load_lds16(Bgp + k0, Bl);
        __syncthreads();

        const int arow2 = wv * 8 + (lr >> 1);
        bf16x8 af = __builtin_bit_cast(bf16x8,
            *(const u16x8*)(As + arow2 * 64 + cidx * 8));
#pragma unroll
        for (int ni = 0; ni < 4; ++ni) {
            const int brow2 = ni * 8 + (lr >> 1);
            bf16x8 bfr = __builtin_bit_cast(bf16x8,
                *(const u16x8*)(Bs + brow2 * 64 + cidx * 8));
            acc[ni] = __builtin_amdgcn_mfma_f32_16x16x32_bf16(af, bfr, acc[ni], 0, 0, 0);
        }
        __syncthreads();
    }

#pragma unroll
    for (int ni = 0; ni < 4; ++ni) {
        const int n = n0 + ni * 16 + lr;
        const int mbase = m0 + wv * 16 + kg * 4;
#pragma unroll
        for (int rg = 0; rg < 4; ++rg)
            Pbf[(size_t)(mbase + rg) * 256 + n] = f2bf(acc[ni][rg]);
    }
}

// ---------------- main i8 GEMM + fused epilogue ----------------------------
// 128x128 tile, BK=64 i8. Swizzled LDS, P pre-gathered to LDS stash, NT out.
__global__ void gemm_i8_kernel(const signed char* __restrict__ Xq, // [M,K]
                               const signed char* __restrict__ Qb, // [N,K]
                               const float* __restrict__ arow,     // [M]
                               const int* __restrict__ codes,      // [N]
                               const float* __restrict__ scales,   // [N]
                               const float* __restrict__ bias,     // [N]
                               const unsigned short* __restrict__ Pbf, // [M,256] bf16
                               float* __restrict__ out,            // [M,N]
                               int M, int N, int K) {
    __shared__ __align__(16) signed char As[128 * 64];
    __shared__ __align__(16) signed char Bs[128 * 64];
    __shared__ unsigned short Pst[64 * 256];  // stash [j][tid], 32 KB

    const int tid  = threadIdx.x;
    const int lane = tid & 63;
    const int wv   = tid >> 6;
    const int wrow = wv >> 1;
    const int wcol = wv & 1;
    const int m0 = blockIdx.y * 128;
    const int n0 = blockIdx.x * 128;
    const int lr = lane & 15;
    const int kg = lane >> 4;
    const int swz = (lr >> 1) & 7;
    const int cidx = (((lr & 1) << 2) | kg) ^ swz;

    // ---- pre-loop: epilogue scalars + P gather into LDS stash -------------
    int   cc[4];
    float rr[4], so[4], bv[4];
#pragma unroll
    for (int ni = 0; ni < 4; ++ni) {
        const int n = n0 + wcol * 64 + ni * 16 + lr;
        const int code = codes[n];
        cc[ni] = code & 0xFF;
        rr[ni] = (float)((code >> 8) & 0xFFFF) * (1.0f / 65535.0f);
        so[ni] = scales[n] * (1.0f / 127.0f);
        bv[ni] = bias[n];
    }
#pragma unroll
    for (int ni = 0; ni < 4; ++ni)
#pragma unroll
        for (int mi = 0; mi < 4; ++mi) {
            const int mb = m0 + wrow * 64 + mi * 16 + kg * 4;
#pragma unroll
            for (int rg = 0; rg < 4; ++rg) {
                unsigned short pv = Pbf[(size_t)(mb + rg) * 256 + cc[ni]];
                Pst[(ni * 16 + mi * 4 + rg) * 256 + tid] = pv;  // own slot, no sync
            }
        }

    i32x4 acc[4][4];
#pragma unroll
    for (int mi = 0; mi < 4; ++mi)
#pragma unroll
        for (int ni = 0; ni < 4; ++ni)
            acc[mi][ni] = (i32x4){0, 0, 0, 0};

    // ---- staging: 512 slots/side, 2 per thread, swizzled global source ----
    const int p0 = tid, p1 = tid + 256;
    const int ga0 = swz_decode(p0, 64);   // row*64 + chunk*16 (bytes in tile)
    const int ga1 = swz_decode(p1, 64);
    const signed char* Ag0 = Xq + (size_t)m0 * K + (ga0 >> 6) * K + (ga0 & 63);
    const signed char* Ag1 = Xq + (size_t)m0 * K + (ga1 >> 6) * K + (ga1 & 63);
    const signed char* Bg0 = Qb + (size_t)n0 * K + (ga0 >> 6) * K + (ga0 & 63);
    const signed char* Bg1 = Qb + (size_t)n0 * K + (ga1 >> 6) * K + (ga1 & 63);
    signed char* Al0 = As + p0 * 16;
    signed char* Al1 = As + p1 * 16;
    signed char* Bl0 = Bs + p0 * 16;
    signed char* Bl1 = Bs + p1 * 16;

    for (int k0 = 0; k0 < K; k0 += 64) {
        load_lds16(Ag0 + k0, Al0);
        load_lds16(Ag1 + k0, Al1);
        load_lds16(Bg0 + k0, Bl0);
        load_lds16(Bg1 + k0, Bl1);
        __syncthreads();

        i32x4 af[4], bfr[4];
#pragma unroll
        for (int mi = 0; mi < 4; ++mi) {
            const int r2 = wrow * 32 + mi * 8 + (lr >> 1);
            af[mi] = *(const i32x4*)(As + r2 * 128 + cidx * 16);
        }
#pragma unroll
        for (int ni = 0; ni < 4; ++ni) {
            const int r2 = wcol * 32 + ni * 8 + (lr >> 1);
            bfr[ni] = *(const i32x4*)(Bs + r2 * 128 + cidx * 16);
        }
#pragma unroll
        for (int mi = 0; mi < 4; ++mi)
#pragma unroll
            for (int ni = 0; ni < 4; ++ni)
                acc[mi][ni] = __builtin_amdgcn_mfma_i32_16x16x64_i8(
                    af[mi], bfr[ni], acc[mi][ni], 0, 0, 0);
        __syncthreads();
    }

    float av[4][4];
#pragma unroll
    for (int mi = 0; mi < 4; ++mi)
#pragma unroll
        for (int rg = 0; rg < 4; ++rg)
            av[mi][rg] = arow[m0 + wrow * 64 + mi * 16 + kg * 4 + rg];

#pragma unroll
    for (int ni = 0; ni < 4; ++ni) {
        const int n = n0 + wcol * 64 + ni * 16 + lr;
#pragma unroll
        for (int mi = 0; mi < 4; ++mi) {
            const int mbase = m0 + wrow * 64 + mi * 16 + kg * 4;
#pragma unroll
            for (int rg = 0; rg < 4; ++rg) {
                const float pf = bf2f(Pst[(ni * 16 + mi * 4 + rg) * 256 + tid]);
                const float y = av[mi][rg] * so[ni] * (float)acc[mi][ni][rg]
                              + rr[ni] * pf + bv[ni];
                __builtin_nontemporal_store(y, &out[(size_t)(mbase + rg) * N + n]);
            }
        }
    }
}

// ---------------------------------------------------------------------------
extern "C" void kernel_launch(void* const* d_in, const int* in_sizes, int n_in,
                              void* d_out, int out_size, void* d_ws, size_t ws_size,
                              hipStream_t stream) {
    const float* x        = (const float*)d_in[0];
    const int*   codes    = (const int*)d_in[1];
    const float* basis    = (const float*)d_in[2];
    const int*   q        = (const int*)d_in[3];
    const float* scales   = (const float*)d_in[4];
    const float* bias     = (const float*)d_in[5];
    float* out = (float*)d_out;

    const int BASIS = 256;
    const int K = in_sizes[2] / BASIS;   // 4096
    const int N = in_sizes[1];           // 4096
    const int M = in_sizes[0] / K;       // 8192

    // ws layout (region A reused: Xb bf16 first, Xq i8 overwrites it later)
    char* ws = (char*)d_ws;
    unsigned short* Xb = (unsigned short*)ws;            // [M,K] bf16, 64 MiB
    signed char*    Xq = (signed char*)ws;               // [M,K] i8 (aliases Xb)
    size_t off = (size_t)M * K * 2;
    signed char* Qb = (signed char*)(ws + off);          // [N,K] i8, 16 MiB
    off += (size_t)N * K;
    unsigned short* Pbf = (unsigned short*)(ws + off);   // [M,256] bf16, 4 MiB
    off += (size_t)M * 256 * 2;
    float* Arow = (float*)(ws + off);                    // [M] fp32
    off += (size_t)M * sizeof(float);
    unsigned short* Bb = (unsigned short*)(ws + off);    // [256,K] bf16, 2 MiB

    // 1. x -> bf16
    cvt_bf16_kernel<<<4096, 256, 0, stream>>>((const float4*)x, (ushort4*)Xb,
                                              M * K / 4);
    // 2. basis -> bf16
    cvt_bf16_kernel<<<1024, 256, 0, stream>>>((const float4*)basis, (ushort4*)Bb,
                                              BASIS * K / 4);
    // 3. P = Xb @ Bb^T
    p_gemm_kernel<<<dim3(BASIS / 64, M / 64), 256, 0, stream>>>(Xb, Bb, Pbf, M, K);
    // 4. residual -> i8
    pack_q_kernel<<<(N * K / 4 + 255) / 256, 256, 0, stream>>>(
        (const int4*)q, (unsigned int*)Qb, N * K / 4);
    // 5. x -> i8 (overwrites Xb region; stream-ordered after p_gemm)
    quant_x_kernel<<<M, 256, 0, stream>>>(x, Xq, Arow, K);
    // 6. main GEMM + fused epilogue
    gemm_i8_kernel<<<dim3(N / 128, M / 128), 256, 0, stream>>>(
        Xq, Qb, Arow, codes, scales, bias, Pbf, out, M, N, K);
}

// Round 5
// 489.598 us; speedup vs baseline: 1.4818x; 1.0932x over previous
//
#include <hip/hip_runtime.h>

// ---------------------------------------------------------------------------
// BitfieldLinear via rank-structure split:
//   y = r_n * P[m, c_n] + (a_m * s_n/127) * (xq @ qb^T) + bias
//   P = x @ basis^T  (bf16 MFMA, stored bf16 [M,256])
// R5: p_gemm rewritten fat (32x256 tile, fp32-A staging, 256 blocks);
//     gemm_i8 widened to 128x256 tile (wave 64x128), epilogue P gather.
// ---------------------------------------------------------------------------

typedef __bf16 bf16x8 __attribute__((ext_vector_type(8)));
typedef float f32x4 __attribute__((ext_vector_type(4)));
typedef int i32x4 __attribute__((ext_vector_type(4)));
typedef unsigned short u16x8 __attribute__((ext_vector_type(8)));

__device__ __forceinline__ unsigned short f2bf(float f) {
    union { float f; unsigned int u; } c; c.f = f;
    unsigned int u = c.u;
    u += 0x7fffu + ((u >> 16) & 1u);
    return (unsigned short)(u >> 16);
}
__device__ __forceinline__ float bf2f(unsigned short h) {
    union { unsigned int u; float f; } c; c.u = ((unsigned int)h) << 16;
    return c.f;
}

__device__ __forceinline__ void load_lds16(const void* g, void* l) {
    __builtin_amdgcn_global_load_lds(
        (__attribute__((address_space(1))) void*)(void*)g,
        (__attribute__((address_space(3))) void*)l,
        16, 0, 0);
}

// r4-verified swizzle for 64-B-row tiles (0 conflicts measured):
// physical 16B-slot p -> (row, chunk) byte offset; 8-slot groups span 2 rows.
__device__ __forceinline__ int swz_decode(int p, int row_bytes) {
    const int g = p >> 3, t = p & 7, v = t ^ (g & 7);
    const int row = g * 2 + (v >> 2), chunk = v & 3;
    return row * row_bytes + chunk * 16;
}

// ---------------- basis fp32 -> bf16 ---------------------------------------
__global__ void cvt_bf16_kernel(const float4* __restrict__ in4,
                                ushort4* __restrict__ out4, int n4) {
    int i = blockIdx.x * blockDim.x + threadIdx.x;
    const int stride = gridDim.x * blockDim.x;
    for (; i < n4; i += stride) {
        float4 v = in4[i];
        ushort4 o;
        o.x = f2bf(v.x); o.y = f2bf(v.y); o.z = f2bf(v.z); o.w = f2bf(v.w);
        out4[i] = o;
    }
}

// ---------------- per-row int8 quantization of x ---------------------------
__global__ void quant_x_kernel(const float* __restrict__ x,
                               signed char* __restrict__ xq,
                               float* __restrict__ arow, int K) {
    const int m = blockIdx.x;
    const float* row = x + (size_t)m * K;
    const int base = threadIdx.x * 16;
    float4 v[4];
#pragma unroll
    for (int j = 0; j < 4; ++j) v[j] = *(const float4*)(row + base + j * 4);

    float lmax = 0.f;
#pragma unroll
    for (int j = 0; j < 4; ++j) {
        lmax = fmaxf(lmax, fabsf(v[j].x));
        lmax = fmaxf(lmax, fabsf(v[j].y));
        lmax = fmaxf(lmax, fabsf(v[j].z));
        lmax = fmaxf(lmax, fabsf(v[j].w));
    }
#pragma unroll
    for (int off = 32; off; off >>= 1)
        lmax = fmaxf(lmax, __shfl_xor(lmax, off));
    __shared__ float smax[4];
    if ((threadIdx.x & 63) == 0) smax[threadIdx.x >> 6] = lmax;
    __syncthreads();
    const float mx = fmaxf(fmaxf(smax[0], smax[1]), fmaxf(smax[2], smax[3]));
    const float inv = mx > 0.f ? 127.0f / mx : 0.0f;
    if (threadIdx.x == 0) arow[m] = mx * (1.0f / 127.0f);

    union { signed char c[16]; i32x4 w; } pk;
#pragma unroll
    for (int j = 0; j < 4; ++j) {
        pk.c[j * 4 + 0] = (signed char)(int)rintf(v[j].x * inv);
        pk.c[j * 4 + 1] = (signed char)(int)rintf(v[j].y * inv);
        pk.c[j * 4 + 2] = (signed char)(int)rintf(v[j].z * inv);
        pk.c[j * 4 + 3] = (signed char)(int)rintf(v[j].w * inv);
    }
    *(i32x4*)(xq + (size_t)m * K + base) = pk.w;
}

// ---------------- pack residual int32 -> int8 (q-128) ----------------------
__global__ void pack_q_kernel(const int4* __restrict__ q4,
                              unsigned int* __restrict__ out, int n4) {
    const int i = blockIdx.x * blockDim.x + threadIdx.x;
    if (i >= n4) return;
    int4 a = q4[i];
    unsigned int w = ((unsigned)(a.x - 128) & 0xFFu)
                   | (((unsigned)(a.y - 128) & 0xFFu) << 8)
                   | (((unsigned)(a.z - 128) & 0xFFu) << 16)
                   | (((unsigned)(a.w - 128) & 0xFFu) << 24);
    out[i] = w;
}

// ---------------- P = x @ basis^T, bf16 out --------------------------------
// Tile: 32 rows (M) x 256 cols (ALL of basis), BK=64. 256 blocks (M/32).
// A staged as fp32 (direct from x, cvt in-loop); B staged bf16. XOR swizzle.
// Wave wv covers cols wv*64..+63 (4 col-tiles) x 32 rows (2 row-tiles).
__global__ __launch_bounds__(256) void
p_gemm_kernel(const float* __restrict__ x,           // [M,K] fp32
              const unsigned short* __restrict__ Bb, // [256,K] bf16
              unsigned short* __restrict__ Pbf,      // [M,256] bf16
              int M, int K) {
    __shared__ __align__(16) float As[32 * 64];            // 8 KB, 256B rows
    __shared__ __align__(16) unsigned short Bs[256 * 64];  // 32 KB, 128B rows

    const int tid  = threadIdx.x;
    const int lane = tid & 63;
    const int wv   = tid >> 6;
    const int m0 = blockIdx.x * 32;
    const int lr = lane & 15;
    const int kg = lane >> 4;

    f32x4 acc[2][4];
#pragma unroll
    for (int mi = 0; mi < 2; ++mi)
#pragma unroll
        for (int ni = 0; ni < 4; ++ni)
            acc[mi][ni] = (f32x4){0.f, 0.f, 0.f, 0.f};

    // A staging: 512 slots (32 rows x 16 chunks of 4 fp32), 2/thread.
    // slot p: row=p>>4, logical chunk=p&15, source chunk = logical ^ (row&15).
    int aRow[2], aSrc[2];
#pragma unroll
    for (int j = 0; j < 2; ++j) {
        const int p = tid + 256 * j;
        aRow[j] = p >> 4;
        aSrc[j] = (p & 15) ^ (aRow[j] & 15);
    }
    // B staging: 2048 slots (256 rows x 8 chunks of 8 bf16), 8/thread.
    int bRow[8], bSrc[8];
#pragma unroll
    for (int j = 0; j < 8; ++j) {
        const int p = tid + 256 * j;
        bRow[j] = p >> 3;
        bSrc[j] = (p & 7) ^ (bRow[j] & 7);
    }

    for (int k0 = 0; k0 < K; k0 += 64) {
#pragma unroll
        for (int j = 0; j < 2; ++j)
            load_lds16(x + (size_t)(m0 + aRow[j]) * K + k0 + aSrc[j] * 4,
                       (char*)As + (tid + 256 * j) * 16);
#pragma unroll
        for (int j = 0; j < 8; ++j)
            load_lds16(Bb + (size_t)bRow[j] * K + k0 + bSrc[j] * 8,
                       (char*)Bs + (tid + 256 * j) * 16);
        __syncthreads();

#pragma unroll
        for (int s = 0; s < 2; ++s) {
            bf16x8 af[2];
#pragma unroll
            for (int mi = 0; mi < 2; ++mi) {
                const int r = mi * 16 + lr;
                const int c0 = s * 8 + kg * 2;
                const int ph0 = c0 ^ (r & 15);
                const int ph1 = (c0 + 1) ^ (r & 15);
                f32x4 lo = *(const f32x4*)(As + r * 64 + ph0 * 4);
                f32x4 hi = *(const f32x4*)(As + r * 64 + ph1 * 4);
                bf16x8 a;
                a[0] = (__bf16)lo[0]; a[1] = (__bf16)lo[1];
                a[2] = (__bf16)lo[2]; a[3] = (__bf16)lo[3];
                a[4] = (__bf16)hi[0]; a[5] = (__bf16)hi[1];
                a[6] = (__bf16)hi[2]; a[7] = (__bf16)hi[3];
                af[mi] = a;
            }
#pragma unroll
            for (int ni = 0; ni < 4; ++ni) {
                const int rb = wv * 64 + ni * 16 + lr;
                const int ph = (s * 4 + kg) ^ (rb & 7);
                bf16x8 bfr = __builtin_bit_cast(bf16x8,
                    *(const u16x8*)(Bs + rb * 64 + ph * 8));
#pragma unroll
                for (int mi = 0; mi < 2; ++mi)
                    acc[mi][ni] = __builtin_amdgcn_mfma_f32_16x16x32_bf16(
                        af[mi], bfr, acc[mi][ni], 0, 0, 0);
            }
        }
        __syncthreads();
    }

#pragma unroll
    for (int ni = 0; ni < 4; ++ni) {
        const int n = wv * 64 + ni * 16 + lr;
#pragma unroll
        for (int mi = 0; mi < 2; ++mi) {
            const int mbase = m0 + mi * 16 + kg * 4;
#pragma unroll
            for (int rg = 0; rg < 4; ++rg)
                Pbf[(size_t)(mbase + rg) * 256 + n] = f2bf(acc[mi][ni][rg]);
        }
    }
}

// ---------------- main i8 GEMM + fused epilogue ----------------------------
// 128(M) x 256(N) tile, BK=64. 4 waves 2x2; wave = 64 rows x 128 cols
// (af[4], bfr[8], acc[4][8]). Swizzled LDS, epilogue P gather, NT stores.
__global__ __launch_bounds__(256, 2) void
gemm_i8_kernel(const signed char* __restrict__ Xq, // [M,K]
               const signed char* __restrict__ Qb, // [N,K]
               const float* __restrict__ arow,     // [M]
               const int* __restrict__ codes,      // [N]
               const float* __restrict__ scales,   // [N]
               const float* __restrict__ bias,     // [N]
               const unsigned short* __restrict__ Pbf, // [M,256] bf16
               float* __restrict__ out,            // [M,N]
               int M, int N, int K) {
    __shared__ __align__(16) signed char As[128 * 64];  //  8 KB
    __shared__ __align__(16) signed char Bs[256 * 64];  // 16 KB

    const int tid  = threadIdx.x;
    const int lane = tid & 63;
    const int wv   = tid >> 6;
    const int wr   = wv >> 1;         // 0..1 (row half)
    const int wc   = wv & 1;          // 0..1 (col half)
    const int m0 = blockIdx.x * 128;  // m-major grid: consecutive blocks share n0
    const int n0 = blockIdx.y * 256;
    const int lr = lane & 15;
    const int kg = lane >> 4;
    const int cidx = (((lr & 1) << 2) | kg) ^ ((lr >> 1) & 7);

    i32x4 acc[4][8];
#pragma unroll
    for (int mi = 0; mi < 4; ++mi)
#pragma unroll
        for (int ni = 0; ni < 8; ++ni)
            acc[mi][ni] = (i32x4){0, 0, 0, 0};

    // A: 512 slots (2/thread); B: 1024 slots (4/thread). 64-B rows, r4 swizzle.
    int gaOff[2], gbOff[4];
#pragma unroll
    for (int j = 0; j < 2; ++j) gaOff[j] = swz_decode(tid + 256 * j, 64);
#pragma unroll
    for (int j = 0; j < 4; ++j) gbOff[j] = swz_decode(tid + 256 * j, 64);

    for (int k0 = 0; k0 < K; k0 += 64) {
#pragma unroll
        for (int j = 0; j < 2; ++j)
            load_lds16(Xq + (size_t)(m0 + (gaOff[j] >> 6)) * K + (gaOff[j] & 63) + k0,
                       As + (tid + 256 * j) * 16);
#pragma unroll
        for (int j = 0; j < 4; ++j)
            load_lds16(Qb + (size_t)(n0 + (gbOff[j] >> 6)) * K + (gbOff[j] & 63) + k0,
                       Bs + (tid + 256 * j) * 16);
        __syncthreads();

        i32x4 af[4], bfr[8];
#pragma unroll
        for (int mi = 0; mi < 4; ++mi) {
            const int r2 = wr * 32 + mi * 8 + (lr >> 1);
            af[mi] = *(const i32x4*)(As + r2 * 128 + cidx * 16);
        }
#pragma unroll
        for (int ni = 0; ni < 8; ++ni) {
            const int r2 = wc * 64 + ni * 8 + (lr >> 1);
            bfr[ni] = *(const i32x4*)(Bs + r2 * 128 + cidx * 16);
        }
#pragma unroll
        for (int mi = 0; mi < 4; ++mi)
#pragma unroll
            for (int ni = 0; ni < 8; ++ni)
                acc[mi][ni] = __builtin_amdgcn_mfma_i32_16x16x64_i8(
                    af[mi], bfr[ni], acc[mi][ni], 0, 0, 0);
        __syncthreads();
    }

    // ---- epilogue: per-row x scales, per-col decode, P gather, NT store ---
    float av[4][4];
#pragma unroll
    for (int mi = 0; mi < 4; ++mi)
#pragma unroll
        for (int rg = 0; rg < 4; ++rg)
            av[mi][rg] = arow[m0 + wr * 64 + mi * 16 + kg * 4 + rg];

#pragma unroll
    for (int ni = 0; ni < 8; ++ni) {
        const int n = n0 + wc * 128 + ni * 16 + lr;
        const int code = codes[n];
        const int cc = code & 0xFF;
        const float rr = (float)((code >> 8) & 0xFFFF) * (1.0f / 65535.0f);
        const float so = scales[n] * (1.0f / 127.0f);
        const float bv = bias[n];
#pragma unroll
        for (int mi = 0; mi < 4; ++mi) {
            const int mbase = m0 + wr * 64 + mi * 16 + kg * 4;
            unsigned short pv[4];
#pragma unroll
            for (int rg = 0; rg < 4; ++rg)
                pv[rg] = Pbf[(size_t)(mbase + rg) * 256 + cc];
#pragma unroll
            for (int rg = 0; rg < 4; ++rg) {
                const float y = av[mi][rg] * so * (float)acc[mi][ni][rg]
                              + rr * bf2f(pv[rg]) + bv;
                __builtin_nontemporal_store(y, &out[(size_t)(mbase + rg) * N + n]);
            }
        }
    }
}

// ---------------------------------------------------------------------------
extern "C" void kernel_launch(void* const* d_in, const int* in_sizes, int n_in,
                              void* d_out, int out_size, void* d_ws, size_t ws_size,
                              hipStream_t stream) {
    const float* x        = (const float*)d_in[0];
    const int*   codes    = (const int*)d_in[1];
    const float* basis    = (const float*)d_in[2];
    const int*   q        = (const int*)d_in[3];
    const float* scales   = (const float*)d_in[4];
    const float* bias     = (const float*)d_in[5];
    float* out = (float*)d_out;

    const int BASIS = 256;
    const int K = in_sizes[2] / BASIS;   // 4096
    const int N = in_sizes[1];           // 4096
    const int M = in_sizes[0] / K;       // 8192

    char* ws = (char*)d_ws;
    signed char* Xq = (signed char*)ws;                  // [M,K] i8, 33.5 MB
    size_t off = (size_t)M * K;
    signed char* Qb = (signed char*)(ws + off);          // [N,K] i8, 16.7 MB
    off += (size_t)N * K;
    unsigned short* Pbf = (unsigned short*)(ws + off);   // [M,256] bf16, 4 MB
    off += (size_t)M * 256 * 2;
    float* Arow = (float*)(ws + off);                    // [M] fp32
    off += (size_t)M * sizeof(float);
    unsigned short* Bb = (unsigned short*)(ws + off);    // [256,K] bf16, 2 MB

    // 1. basis -> bf16 (2 MB)
    cvt_bf16_kernel<<<1024, 256, 0, stream>>>((const float4*)basis, (ushort4*)Bb,
                                              BASIS * K / 4);
    // 2. P = x @ basis^T  (reads x fp32 directly)
    p_gemm_kernel<<<M / 32, 256, 0, stream>>>(x, Bb, Pbf, M, K);
    // 3. x -> i8 + per-row scale
    quant_x_kernel<<<M, 256, 0, stream>>>(x, Xq, Arow, K);
    // 4. residual -> i8
    pack_q_kernel<<<(N * K / 4 + 255) / 256, 256, 0, stream>>>(
        (const int4*)q, (unsigned int*)Qb, N * K / 4);
    // 5. main GEMM + fused epilogue
    gemm_i8_kernel<<<dim3(M / 128, N / 256), 256, 0, stream>>>(
        Xq, Qb, Arow, codes, scales, bias, Pbf, out, M, N, K);
}